// Round 1
// baseline (32.532 us; speedup 1.0000x reference)
//
#include <hip/hip_runtime.h>

constexpr int BATCH = 4;
constexpr int NBOX  = 2048;
constexpr int JTILE = 256;   // threads per block, one j each
constexpr int ITILE = 64;    // i-rows per block
constexpr float LOG2E = 1.4426950408889634f;

// params layout: 8 floats per box (AoS, 32B aligned):
//   [ux, uy, s00, s01] [s11, t, pad, pad]
// where sigma = R diag(size/2) R^T and t = 0.25*log2(det sigma)

__global__ __launch_bounds__(256) void precompute_params(
        const float* __restrict__ bboxes,
        const float* __restrict__ angles,
        float* __restrict__ params) {
    int idx = blockIdx.x * 256 + threadIdx.x;
    if (idx >= BATCH * NBOX) return;

    const float4* bp = reinterpret_cast<const float4*>(bboxes + (size_t)idx * 8);
    float4 p01 = bp[0];   // x0 y0 x1 y1
    float4 p23 = bp[1];   // x2 y2 x3 y3

    float cx = (p01.x + p01.z + p23.x + p23.z) * 0.25f;
    float cy = (p01.y + p01.w + p23.y + p23.w) * 0.25f;

    float ang = angles[idx];
    float s = __sinf(ang);
    float c = __cosf(ang);

    // rotate (p - center) by -ang: px = dx*c - dy*s ; py = dx*s + dy*c
    float dx0 = p01.x - cx, dy0 = p01.y - cy;
    float dx1 = p01.z - cx, dy1 = p01.w - cy;
    float dx2 = p23.x - cx, dy2 = p23.y - cy;
    float dx3 = p23.z - cx, dy3 = p23.w - cy;

    float px0 = dx0 * c - dy0 * s, py0 = dx0 * s + dy0 * c;
    float px1 = dx1 * c - dy1 * s, py1 = dx1 * s + dy1 * c;
    float px2 = dx2 * c - dy2 * s, py2 = dx2 * s + dy2 * c;
    float px3 = dx3 * c - dy3 * s, py3 = dx3 * s + dy3 * c;

    float minx = fminf(fminf(px0, px1), fminf(px2, px3));
    float maxx = fmaxf(fmaxf(px0, px1), fmaxf(px2, px3));
    float miny = fminf(fminf(py0, py1), fminf(py2, py3));
    float maxy = fmaxf(fmaxf(py0, py1), fmaxf(py2, py3));

    float w0 = (maxx - minx) * 0.5f;
    float w1 = (maxy - miny) * 0.5f;

    float s00 = c * c * w0 + s * s * w1;
    float s01 = c * s * (w0 - w1);
    float s11 = s * s * w0 + c * c * w1;

    // det(sigma) = w0*w1 exactly (rotation preserves determinant)
    float t = 0.25f * __builtin_amdgcn_logf(w0 * w1);  // log2

    float4* pp = reinterpret_cast<float4*>(params + (size_t)idx * 8);
    pp[0] = make_float4(cx, cy, s00, s01);
    pp[1] = make_float4(s11, t, 0.0f, 0.0f);
}

__global__ __launch_bounds__(256) void pairwise_iou(
        const float* __restrict__ params,
        float* __restrict__ out) {
    const int j  = blockIdx.x * JTILE + threadIdx.x;
    const int i0 = blockIdx.y * ITILE;
    const int b  = blockIdx.z;

    const float4* pj = reinterpret_cast<const float4*>(params + (size_t)(b * NBOX + j) * 8);
    float4 pj0 = pj[0];
    float4 pj1 = pj[1];
    const float ujx = pj0.x, ujy = pj0.y, aj = pj0.z, bj = pj0.w;
    const float dj = pj1.x, tj = pj1.y;

    const float4* pi = reinterpret_cast<const float4*>(params + (size_t)(b * NBOX + i0) * 8);
    float* orow = out + ((size_t)(b * NBOX + i0)) * NBOX + j;

    #pragma unroll 4
    for (int it = 0; it < ITILE; ++it) {
        float4 pi0 = pi[2 * it];       // uniform address -> scalar loads, L2-hot
        float4 pi1 = pi[2 * it + 1];

        float ddx = pi0.x - ujx;
        float ddy = pi0.y - ujy;
        float a   = (pi0.z + aj) * 0.5f;
        float bb  = (pi0.w + bj) * 0.5f;
        float d   = (pi1.x + dj) * 0.5f;
        float ts  = pi1.y + tj;

        float det = a * d - bb * bb;
        float inv = __builtin_amdgcn_rcpf(det);
        inv = (det == 0.0f) ? 0.0f : inv;

        float lg = __builtin_amdgcn_logf(det);          // log2(det)
        float q  = ddx * ddx * d + ddy * ddy * a;       // u_diff^T diag(d,a) u_diff
        // Bd = q*inv/8 + 0.5*ln(det) - 0.25*ln(det_s_i) - 0.25*ln(det_s_j)
        // Bc = exp(-Bd) = exp2( -q*inv*LOG2E/8 - 0.5*log2(det) + t_i + t_j )
        float e  = q * (inv * (-0.125f * LOG2E)) + (ts - 0.5f * lg);
        float bc = __builtin_amdgcn_exp2f(e);

        float om = 1.0f - bc;
        float hd = __builtin_amdgcn_sqrtf(fmaxf(om, 1e-12f));
        orow[(size_t)it * NBOX] = 1.0f - hd;
    }
}

extern "C" void kernel_launch(void* const* d_in, const int* in_sizes, int n_in,
                              void* d_out, int out_size, void* d_ws, size_t ws_size,
                              hipStream_t stream) {
    const float* bboxes = (const float*)d_in[0];
    const float* angles = (const float*)d_in[1];
    float* out    = (float*)d_out;
    float* params = (float*)d_ws;   // needs BATCH*NBOX*8*4 = 256 KB

    dim3 g1((BATCH * NBOX + 255) / 256);
    precompute_params<<<g1, 256, 0, stream>>>(bboxes, angles, params);

    dim3 g2(NBOX / JTILE, NBOX / ITILE, BATCH);
    pairwise_iou<<<g2, 256, 0, stream>>>(params, out);
}

// Round 2
// 25.585 us; speedup vs baseline: 1.2715x; 1.2715x over previous
//
#include <hip/hip_runtime.h>

constexpr int BATCH = 4;
constexpr int NBOX  = 2048;
constexpr int NB    = BATCH * NBOX;     // 8192 boxes
constexpr int TPB   = 256;
constexpr int JQ    = 4;                // j's per thread
constexpr int JSPAN = TPB * JQ;         // 1024 j per block
constexpr int ITILE = 16;               // i rows per block
constexpr float NL8E = -0.18033688011112042f;  // -log2(e)/8

// SoA params in d_ws, 6 arrays of NB floats:
//   ux, uy, A=s00/2, B=s01/2, D=s11/2, R=(w0*w1)^(1/4)
// sigma = R diag(size/2) R^T halved so s = (sig_i+sig_j)/2 = A_i+A_j etc.

__global__ __launch_bounds__(TPB) void precompute_params(
        const float* __restrict__ bboxes,
        const float* __restrict__ angles,
        float* __restrict__ P) {
    int idx = blockIdx.x * TPB + threadIdx.x;
    if (idx >= NB) return;

    const float4* bp = reinterpret_cast<const float4*>(bboxes) + (size_t)idx * 2;
    float4 p01 = bp[0];   // x0 y0 x1 y1
    float4 p23 = bp[1];   // x2 y2 x3 y3

    float cx = (p01.x + p01.z + p23.x + p23.z) * 0.25f;
    float cy = (p01.y + p01.w + p23.y + p23.w) * 0.25f;

    float ang = angles[idx];
    float s = __sinf(ang);
    float c = __cosf(ang);

    float dx0 = p01.x - cx, dy0 = p01.y - cy;
    float dx1 = p01.z - cx, dy1 = p01.w - cy;
    float dx2 = p23.x - cx, dy2 = p23.y - cy;
    float dx3 = p23.z - cx, dy3 = p23.w - cy;

    float px0 = dx0 * c - dy0 * s, py0 = dx0 * s + dy0 * c;
    float px1 = dx1 * c - dy1 * s, py1 = dx1 * s + dy1 * c;
    float px2 = dx2 * c - dy2 * s, py2 = dx2 * s + dy2 * c;
    float px3 = dx3 * c - dy3 * s, py3 = dx3 * s + dy3 * c;

    float minx = fminf(fminf(px0, px1), fminf(px2, px3));
    float maxx = fmaxf(fmaxf(px0, px1), fmaxf(px2, px3));
    float miny = fminf(fminf(py0, py1), fminf(py2, py3));
    float maxy = fmaxf(fmaxf(py0, py1), fmaxf(py2, py3));

    float w0 = (maxx - minx) * 0.5f;
    float w1 = (maxy - miny) * 0.5f;

    P[0 * NB + idx] = cx;
    P[1 * NB + idx] = cy;
    P[2 * NB + idx] = 0.5f * (c * c * w0 + s * s * w1);
    P[3 * NB + idx] = 0.5f * (c * s * (w0 - w1));
    P[4 * NB + idx] = 0.5f * (s * s * w0 + c * c * w1);
    // (det sigma)^(1/4) = (w0*w1)^(1/4); det invariant under rotation
    P[5 * NB + idx] = __builtin_amdgcn_sqrtf(__builtin_amdgcn_sqrtf(w0 * w1));
}

__device__ __forceinline__ float pair_iou(
        float iux, float iuy, float ia, float ib, float id, float ir,
        float jux, float juy, float ja, float jb, float jd, float jr) {
    float ddx = iux - jux;
    float ddy = iuy - juy;
    float a   = ia + ja;
    float bb  = ib + jb;
    float d   = id + jd;
    float det = a * d - bb * bb;
    float rsq = __builtin_amdgcn_rsqf(det);      // det^{-1/2}
    float inv = rsq * rsq;                       // 1/det
    float q   = (ddx * ddx) * d + (ddy * ddy) * a;
    float e   = (q * inv) * NL8E;                // -q/(8 det) * log2(e)
    // Bc = exp(-Bd) = exp2(e) * (det_si*det_sj)^{1/4} / sqrt(det)
    float bc  = __builtin_amdgcn_exp2f(e) * (rsq * (ir * jr));
    float hd  = __builtin_amdgcn_sqrtf(fmaxf(1.0f - bc, 1e-12f));
    return 1.0f - hd;
}

__global__ __launch_bounds__(TPB) void pairwise_iou(
        const float* __restrict__ P,
        float* __restrict__ out) {
    const int tid = threadIdx.x;
    const int b   = blockIdx.z;
    const int i0  = blockIdx.y * ITILE;
    const int j0  = blockIdx.x * JSPAN + tid * JQ;

    // stage ITILE i-boxes (6 floats each) into LDS, SoA
    __shared__ float sp[6][ITILE];
    if (tid < 6 * ITILE) {
        int f = tid >> 4;          // which field
        int k = tid & (ITILE - 1); // which box
        sp[f][k] = P[f * NB + b * NBOX + i0 + k];
    }

    const int gj = b * NBOX + j0;
    float4 jux = *reinterpret_cast<const float4*>(P + 0 * NB + gj);
    float4 juy = *reinterpret_cast<const float4*>(P + 1 * NB + gj);
    float4 jA  = *reinterpret_cast<const float4*>(P + 2 * NB + gj);
    float4 jB  = *reinterpret_cast<const float4*>(P + 3 * NB + gj);
    float4 jD  = *reinterpret_cast<const float4*>(P + 4 * NB + gj);
    float4 jR  = *reinterpret_cast<const float4*>(P + 5 * NB + gj);
    __syncthreads();

    float* orow = out + ((size_t)(b * NBOX + i0)) * NBOX + j0;

    #pragma unroll 4
    for (int it = 0; it < ITILE; ++it) {
        float iux = sp[0][it];   // all-lane broadcast, conflict-free
        float iuy = sp[1][it];
        float ia  = sp[2][it];
        float ibv = sp[3][it];
        float id  = sp[4][it];
        float ir  = sp[5][it];

        float4 r;
        r.x = pair_iou(iux, iuy, ia, ibv, id, ir, jux.x, juy.x, jA.x, jB.x, jD.x, jR.x);
        r.y = pair_iou(iux, iuy, ia, ibv, id, ir, jux.y, juy.y, jA.y, jB.y, jD.y, jR.y);
        r.z = pair_iou(iux, iuy, ia, ibv, id, ir, jux.z, juy.z, jA.z, jB.z, jD.z, jR.z);
        r.w = pair_iou(iux, iuy, ia, ibv, id, ir, jux.w, juy.w, jA.w, jB.w, jD.w, jR.w);

        *reinterpret_cast<float4*>(orow + (size_t)it * NBOX) = r;
    }
}

extern "C" void kernel_launch(void* const* d_in, const int* in_sizes, int n_in,
                              void* d_out, int out_size, void* d_ws, size_t ws_size,
                              hipStream_t stream) {
    const float* bboxes = (const float*)d_in[0];
    const float* angles = (const float*)d_in[1];
    float* out = (float*)d_out;
    float* P   = (float*)d_ws;   // 6 * 8192 * 4 = 192 KB

    dim3 g1(NB / TPB);
    precompute_params<<<g1, TPB, 0, stream>>>(bboxes, angles, P);

    dim3 g2(NBOX / JSPAN, NBOX / ITILE, BATCH);
    pairwise_iou<<<g2, TPB, 0, stream>>>(P, out);
}

// Round 3
// 24.095 us; speedup vs baseline: 1.3502x; 1.0618x over previous
//
#include <hip/hip_runtime.h>

constexpr int BATCH = 4;
constexpr int NBOX  = 2048;
constexpr int TPB   = 256;
constexpr int JQ    = 4;                // j's per thread
constexpr int JSPAN = TPB * JQ;         // 1024 j per block
constexpr int ITILE = 16;               // i rows per block
constexpr float NL8E = -0.18033688011112042f;  // -log2(e)/8

// ---- per-box params: u, A=s00/2, B=s01/2, D=s11/2, R=(det sigma)^{1/4} ----
__device__ __forceinline__ void box_params(
        const float4* __restrict__ bb4, const float* __restrict__ angles, int idx,
        float& cx, float& cy, float& A, float& B, float& D, float& R) {
    float4 p01 = bb4[2 * idx];
    float4 p23 = bb4[2 * idx + 1];

    cx = (p01.x + p01.z + p23.x + p23.z) * 0.25f;
    cy = (p01.y + p01.w + p23.y + p23.w) * 0.25f;

    float ang = angles[idx];
    float s = __sinf(ang);
    float c = __cosf(ang);

    float dx0 = p01.x - cx, dy0 = p01.y - cy;
    float dx1 = p01.z - cx, dy1 = p01.w - cy;
    float dx2 = p23.x - cx, dy2 = p23.y - cy;
    float dx3 = p23.z - cx, dy3 = p23.w - cy;

    float px0 = dx0 * c - dy0 * s, py0 = dx0 * s + dy0 * c;
    float px1 = dx1 * c - dy1 * s, py1 = dx1 * s + dy1 * c;
    float px2 = dx2 * c - dy2 * s, py2 = dx2 * s + dy2 * c;
    float px3 = dx3 * c - dy3 * s, py3 = dx3 * s + dy3 * c;

    float minx = fminf(fminf(px0, px1), fminf(px2, px3));
    float maxx = fmaxf(fmaxf(px0, px1), fmaxf(px2, px3));
    float miny = fminf(fminf(py0, py1), fminf(py2, py3));
    float maxy = fmaxf(fmaxf(py0, py1), fmaxf(py2, py3));

    float w0 = (maxx - minx) * 0.5f;
    float w1 = (maxy - miny) * 0.5f;

    A = 0.5f * (c * c * w0 + s * s * w1);
    B = 0.5f * (c * s * (w0 - w1));
    D = 0.5f * (s * s * w0 + c * c * w1);
    R = __builtin_amdgcn_sqrtf(__builtin_amdgcn_sqrtf(w0 * w1));  // det^(1/4)
}

// ---- float2 helpers (encourage v_pk_*_f32 packed math) ----
__device__ __forceinline__ float2 f2(float x, float y) { return make_float2(x, y); }
__device__ __forceinline__ float2 add2(float2 a, float2 b) { return f2(a.x + b.x, a.y + b.y); }
__device__ __forceinline__ float2 sub2(float2 a, float2 b) { return f2(a.x - b.x, a.y - b.y); }
__device__ __forceinline__ float2 mul2(float2 a, float2 b) { return f2(a.x * b.x, a.y * b.y); }
__device__ __forceinline__ float2 fma2(float2 a, float2 b, float2 c) {
    return f2(__builtin_fmaf(a.x, b.x, c.x), __builtin_fmaf(a.y, b.y, c.y));
}

// two pairs at once: wave-uniform i-params vs a float2 of j-params
__device__ __forceinline__ float2 pair_duo(
        float iux, float iuy, float ia, float ib, float id, float ir,
        float2 jux, float2 juy, float2 ja, float2 jb, float2 jd, float2 jr) {
    float2 ddx = sub2(f2(iux, iux), jux);
    float2 ddy = sub2(f2(iuy, iuy), juy);
    float2 a   = add2(f2(ia, ia), ja);
    float2 bb  = add2(f2(ib, ib), jb);
    float2 d   = add2(f2(id, id), jd);

    float2 mb2 = mul2(bb, bb);
    float2 det = fma2(a, d, f2(-mb2.x, -mb2.y));
    float2 rsq = f2(__builtin_amdgcn_rsqf(det.x), __builtin_amdgcn_rsqf(det.y));
    float2 inv = mul2(rsq, rsq);

    float2 q   = fma2(mul2(ddy, ddy), a, mul2(mul2(ddx, ddx), d));
    float2 e   = mul2(mul2(q, inv), f2(NL8E, NL8E));
    float2 ex  = f2(__builtin_amdgcn_exp2f(e.x), __builtin_amdgcn_exp2f(e.y));

    float2 bc  = mul2(mul2(ex, rsq), mul2(f2(ir, ir), jr));
    float2 om  = f2(fmaxf(1.0f - bc.x, 1e-12f), fmaxf(1.0f - bc.y, 1e-12f));
    float2 hd  = f2(__builtin_amdgcn_sqrtf(om.x), __builtin_amdgcn_sqrtf(om.y));
    return f2(1.0f - hd.x, 1.0f - hd.y);
}

__global__ __launch_bounds__(TPB, 4) void fused_iou(
        const float* __restrict__ bboxes,
        const float* __restrict__ angles,
        float* __restrict__ out) {
    const int tid = threadIdx.x;
    const int b   = blockIdx.z;
    const int i0  = blockIdx.y * ITILE;
    const int j0  = blockIdx.x * JSPAN + tid * JQ;

    const float4* bb4 = reinterpret_cast<const float4*>(bboxes);

    // i-params: 16 lanes of wave 0 -> LDS (other waves proceed to j-params)
    __shared__ float sp[6][ITILE];
    if (tid < ITILE) {
        float cx, cy, A, B, D, R;
        box_params(bb4, angles, b * NBOX + i0 + tid, cx, cy, A, B, D, R);
        sp[0][tid] = cx; sp[1][tid] = cy; sp[2][tid] = A;
        sp[3][tid] = B;  sp[4][tid] = D;  sp[5][tid] = R;
    }

    // j-params: each thread computes its own 4 boxes into registers
    float jp[6][JQ];
    #pragma unroll
    for (int q = 0; q < JQ; ++q) {
        float cx, cy, A, B, D, R;
        box_params(bb4, angles, b * NBOX + j0 + q, cx, cy, A, B, D, R);
        jp[0][q] = cx; jp[1][q] = cy; jp[2][q] = A;
        jp[3][q] = B;  jp[4][q] = D;  jp[5][q] = R;
    }
    float2 jux0 = f2(jp[0][0], jp[0][1]), jux1 = f2(jp[0][2], jp[0][3]);
    float2 juy0 = f2(jp[1][0], jp[1][1]), juy1 = f2(jp[1][2], jp[1][3]);
    float2 jA0  = f2(jp[2][0], jp[2][1]), jA1  = f2(jp[2][2], jp[2][3]);
    float2 jB0  = f2(jp[3][0], jp[3][1]), jB1  = f2(jp[3][2], jp[3][3]);
    float2 jD0  = f2(jp[4][0], jp[4][1]), jD1  = f2(jp[4][2], jp[4][3]);
    float2 jR0  = f2(jp[5][0], jp[5][1]), jR1  = f2(jp[5][2], jp[5][3]);

    __syncthreads();

    float* orow = out + ((size_t)(b * NBOX + i0)) * NBOX + j0;

    #pragma unroll 4
    for (int it = 0; it < ITILE; ++it) {
        float iux = sp[0][it];   // all-lane broadcast, conflict-free
        float iuy = sp[1][it];
        float ia  = sp[2][it];
        float ibv = sp[3][it];
        float id  = sp[4][it];
        float ir  = sp[5][it];

        float2 r01 = pair_duo(iux, iuy, ia, ibv, id, ir, jux0, juy0, jA0, jB0, jD0, jR0);
        float2 r23 = pair_duo(iux, iuy, ia, ibv, id, ir, jux1, juy1, jA1, jB1, jD1, jR1);

        *reinterpret_cast<float4*>(orow) = make_float4(r01.x, r01.y, r23.x, r23.y);
        orow += NBOX;
    }
}

extern "C" void kernel_launch(void* const* d_in, const int* in_sizes, int n_in,
                              void* d_out, int out_size, void* d_ws, size_t ws_size,
                              hipStream_t stream) {
    const float* bboxes = (const float*)d_in[0];
    const float* angles = (const float*)d_in[1];
    float* out = (float*)d_out;

    dim3 g(NBOX / JSPAN, NBOX / ITILE, BATCH);
    fused_iou<<<g, TPB, 0, stream>>>(bboxes, angles, out);
}

// Round 4
// 21.992 us; speedup vs baseline: 1.4793x; 1.0957x over previous
//
#include <hip/hip_runtime.h>

constexpr int BATCH = 4;
constexpr int NBOX  = 2048;
constexpr int TPB   = 256;
constexpr int JQ    = 2;                // j's per thread (keeps VGPR <= 64)
constexpr int JSPAN = TPB * JQ;         // 512 j per block
constexpr int ITILE = 16;               // i rows per block
constexpr float NL8E = -0.18033688011112042f;  // -log2(e)/8

// ---- per-box params: u, A=s00/2, B=s01/2, D=s11/2, R=(det sigma)^{1/4} ----
__device__ __forceinline__ void box_params(
        const float4* __restrict__ bb4, const float* __restrict__ angles, int idx,
        float& cx, float& cy, float& A, float& B, float& D, float& R) {
    float4 p01 = bb4[2 * idx];
    float4 p23 = bb4[2 * idx + 1];

    cx = (p01.x + p01.z + p23.x + p23.z) * 0.25f;
    cy = (p01.y + p01.w + p23.y + p23.w) * 0.25f;

    float ang = angles[idx];
    float s = __sinf(ang);
    float c = __cosf(ang);

    float dx0 = p01.x - cx, dy0 = p01.y - cy;
    float dx1 = p01.z - cx, dy1 = p01.w - cy;
    float dx2 = p23.x - cx, dy2 = p23.y - cy;
    float dx3 = p23.z - cx, dy3 = p23.w - cy;

    float px0 = dx0 * c - dy0 * s, py0 = dx0 * s + dy0 * c;
    float px1 = dx1 * c - dy1 * s, py1 = dx1 * s + dy1 * c;
    float px2 = dx2 * c - dy2 * s, py2 = dx2 * s + dy2 * c;
    float px3 = dx3 * c - dy3 * s, py3 = dx3 * s + dy3 * c;

    float minx = fminf(fminf(px0, px1), fminf(px2, px3));
    float maxx = fmaxf(fmaxf(px0, px1), fmaxf(px2, px3));
    float miny = fminf(fminf(py0, py1), fminf(py2, py3));
    float maxy = fmaxf(fmaxf(py0, py1), fmaxf(py2, py3));

    float w0 = (maxx - minx) * 0.5f;
    float w1 = (maxy - miny) * 0.5f;

    A = 0.5f * (c * c * w0 + s * s * w1);
    B = 0.5f * (c * s * (w0 - w1));
    D = 0.5f * (s * s * w0 + c * c * w1);
    R = __builtin_amdgcn_sqrtf(__builtin_amdgcn_sqrtf(w0 * w1));  // det^(1/4)
}

// ---- float2 helpers (encourage v_pk_*_f32 packed math) ----
__device__ __forceinline__ float2 f2(float x, float y) { return make_float2(x, y); }
__device__ __forceinline__ float2 add2(float2 a, float2 b) { return f2(a.x + b.x, a.y + b.y); }
__device__ __forceinline__ float2 sub2(float2 a, float2 b) { return f2(a.x - b.x, a.y - b.y); }
__device__ __forceinline__ float2 mul2(float2 a, float2 b) { return f2(a.x * b.x, a.y * b.y); }
__device__ __forceinline__ float2 fma2(float2 a, float2 b, float2 c) {
    return f2(__builtin_fmaf(a.x, b.x, c.x), __builtin_fmaf(a.y, b.y, c.y));
}

// two pairs at once: wave-uniform i-params vs a float2 of j-params
__device__ __forceinline__ float2 pair_duo(
        float iux, float iuy, float ia, float ib, float id, float ir,
        float2 jux, float2 juy, float2 ja, float2 jb, float2 jd, float2 jr) {
    float2 ddx = sub2(f2(iux, iux), jux);
    float2 ddy = sub2(f2(iuy, iuy), juy);
    float2 a   = add2(f2(ia, ia), ja);
    float2 bb  = add2(f2(ib, ib), jb);
    float2 d   = add2(f2(id, id), jd);

    float2 mb2 = mul2(bb, bb);
    float2 det = fma2(a, d, f2(-mb2.x, -mb2.y));
    float2 rsq = f2(__builtin_amdgcn_rsqf(det.x), __builtin_amdgcn_rsqf(det.y));
    float2 inv = mul2(rsq, rsq);

    float2 q   = fma2(mul2(ddy, ddy), a, mul2(mul2(ddx, ddx), d));
    float2 e   = mul2(mul2(q, inv), f2(NL8E, NL8E));
    float2 ex  = f2(__builtin_amdgcn_exp2f(e.x), __builtin_amdgcn_exp2f(e.y));

    float2 bc  = mul2(mul2(ex, rsq), mul2(f2(ir, ir), jr));
    float2 om  = f2(fmaxf(1.0f - bc.x, 1e-12f), fmaxf(1.0f - bc.y, 1e-12f));
    float2 hd  = f2(__builtin_amdgcn_sqrtf(om.x), __builtin_amdgcn_sqrtf(om.y));
    return f2(1.0f - hd.x, 1.0f - hd.y);
}

__global__ __launch_bounds__(TPB, 8) void fused_iou(
        const float* __restrict__ bboxes,
        const float* __restrict__ angles,
        float* __restrict__ out) {
    const int tid = threadIdx.x;
    const int b   = blockIdx.z;
    const int i0  = blockIdx.y * ITILE;
    const int j0  = blockIdx.x * JSPAN + tid * JQ;

    const float4* bb4 = reinterpret_cast<const float4*>(bboxes);

    // i-params: 16 lanes of wave 0 -> LDS (other waves proceed to j-params)
    __shared__ float sp[6][ITILE];
    if (tid < ITILE) {
        float cx, cy, A, B, D, R;
        box_params(bb4, angles, b * NBOX + i0 + tid, cx, cy, A, B, D, R);
        sp[0][tid] = cx; sp[1][tid] = cy; sp[2][tid] = A;
        sp[3][tid] = B;  sp[4][tid] = D;  sp[5][tid] = R;
    }

    // j-params: each thread computes its own 2 boxes into registers
    float c0, c1, y0v, y1v, A0, A1, B0, B1, D0, D1, R0, R1;
    box_params(bb4, angles, b * NBOX + j0 + 0, c0, y0v, A0, B0, D0, R0);
    box_params(bb4, angles, b * NBOX + j0 + 1, c1, y1v, A1, B1, D1, R1);
    float2 jux = f2(c0, c1);
    float2 juy = f2(y0v, y1v);
    float2 jA  = f2(A0, A1);
    float2 jB  = f2(B0, B1);
    float2 jD  = f2(D0, D1);
    float2 jR  = f2(R0, R1);

    __syncthreads();

    float* orow = out + ((size_t)(b * NBOX + i0)) * NBOX + j0;

    #pragma unroll 4
    for (int it = 0; it < ITILE; ++it) {
        float iux = sp[0][it];   // all-lane broadcast, conflict-free
        float iuy = sp[1][it];
        float ia  = sp[2][it];
        float ibv = sp[3][it];
        float id  = sp[4][it];
        float ir  = sp[5][it];

        float2 r = pair_duo(iux, iuy, ia, ibv, id, ir, jux, juy, jA, jB, jD, jR);

        *reinterpret_cast<float2*>(orow) = r;
        orow += NBOX;
    }
}

extern "C" void kernel_launch(void* const* d_in, const int* in_sizes, int n_in,
                              void* d_out, int out_size, void* d_ws, size_t ws_size,
                              hipStream_t stream) {
    const float* bboxes = (const float*)d_in[0];
    const float* angles = (const float*)d_in[1];
    float* out = (float*)d_out;

    dim3 g(NBOX / JSPAN, NBOX / ITILE, BATCH);
    fused_iou<<<g, TPB, 0, stream>>>(bboxes, angles, out);
}

// Round 5
// 21.596 us; speedup vs baseline: 1.5064x; 1.0183x over previous
//
#include <hip/hip_runtime.h>

constexpr int BATCH = 4;
constexpr int NBOX  = 2048;
constexpr int TPB   = 256;
constexpr int JQ    = 2;                // j's per thread (keeps VGPR <= 64)
constexpr int JSPAN = TPB * JQ;         // 512 j per block
constexpr int ITILE = 16;               // i rows per block
constexpr float NL8E = -0.18033688011112042f;  // -log2(e)/8

typedef float f32x2 __attribute__((ext_vector_type(2)));

// ---- per-box params: u, A=s00/2, B=s01/2, D=s11/2, R=(det sigma)^{1/4} ----
__device__ __forceinline__ void box_params(
        const float4* __restrict__ bb4, const float* __restrict__ angles, int idx,
        float& cx, float& cy, float& A, float& B, float& D, float& R) {
    float4 p01 = bb4[2 * idx];
    float4 p23 = bb4[2 * idx + 1];

    cx = (p01.x + p01.z + p23.x + p23.z) * 0.25f;
    cy = (p01.y + p01.w + p23.y + p23.w) * 0.25f;

    float ang = angles[idx];
    float s = __sinf(ang);
    float c = __cosf(ang);

    float dx0 = p01.x - cx, dy0 = p01.y - cy;
    float dx1 = p01.z - cx, dy1 = p01.w - cy;
    float dx2 = p23.x - cx, dy2 = p23.y - cy;
    float dx3 = p23.z - cx, dy3 = p23.w - cy;

    float px0 = dx0 * c - dy0 * s, py0 = dx0 * s + dy0 * c;
    float px1 = dx1 * c - dy1 * s, py1 = dx1 * s + dy1 * c;
    float px2 = dx2 * c - dy2 * s, py2 = dx2 * s + dy2 * c;
    float px3 = dx3 * c - dy3 * s, py3 = dx3 * s + dy3 * c;

    float minx = fminf(fminf(px0, px1), fminf(px2, px3));
    float maxx = fmaxf(fmaxf(px0, px1), fmaxf(px2, px3));
    float miny = fminf(fminf(py0, py1), fminf(py2, py3));
    float maxy = fmaxf(fmaxf(py0, py1), fmaxf(py2, py3));

    float w0 = (maxx - minx) * 0.5f;
    float w1 = (maxy - miny) * 0.5f;

    A = 0.5f * (c * c * w0 + s * s * w1);
    B = 0.5f * (c * s * (w0 - w1));
    D = 0.5f * (s * s * w0 + c * c * w1);
    R = __builtin_amdgcn_sqrtf(__builtin_amdgcn_sqrtf(w0 * w1));  // det^(1/4)
}

// ---- float2 helpers (encourage v_pk_*_f32 packed math) ----
__device__ __forceinline__ float2 f2(float x, float y) { return make_float2(x, y); }
__device__ __forceinline__ float2 add2(float2 a, float2 b) { return f2(a.x + b.x, a.y + b.y); }
__device__ __forceinline__ float2 sub2(float2 a, float2 b) { return f2(a.x - b.x, a.y - b.y); }
__device__ __forceinline__ float2 mul2(float2 a, float2 b) { return f2(a.x * b.x, a.y * b.y); }
__device__ __forceinline__ float2 fma2(float2 a, float2 b, float2 c) {
    return f2(__builtin_fmaf(a.x, b.x, c.x), __builtin_fmaf(a.y, b.y, c.y));
}

// two pairs at once: wave-uniform i-params vs a float2 of j-params
__device__ __forceinline__ float2 pair_duo(
        float iux, float iuy, float ia, float ib, float id, float ir,
        float2 jux, float2 juy, float2 ja, float2 jb, float2 jd, float2 jr) {
    float2 ddx = sub2(f2(iux, iux), jux);
    float2 ddy = sub2(f2(iuy, iuy), juy);
    float2 a   = add2(f2(ia, ia), ja);
    float2 bb  = add2(f2(ib, ib), jb);
    float2 d   = add2(f2(id, id), jd);

    float2 mb2 = mul2(bb, bb);
    float2 det = fma2(a, d, f2(-mb2.x, -mb2.y));
    float2 rsq = f2(__builtin_amdgcn_rsqf(det.x), __builtin_amdgcn_rsqf(det.y));
    float2 inv = mul2(rsq, rsq);

    float2 q   = fma2(mul2(ddy, ddy), a, mul2(mul2(ddx, ddx), d));
    float2 e   = mul2(mul2(q, inv), f2(NL8E, NL8E));
    float2 ex  = f2(__builtin_amdgcn_exp2f(e.x), __builtin_amdgcn_exp2f(e.y));

    float2 bc  = mul2(mul2(ex, rsq), mul2(f2(ir, ir), jr));
    float2 om  = f2(fmaxf(1.0f - bc.x, 1e-12f), fmaxf(1.0f - bc.y, 1e-12f));
    float2 hd  = f2(__builtin_amdgcn_sqrtf(om.x), __builtin_amdgcn_sqrtf(om.y));
    return f2(1.0f - hd.x, 1.0f - hd.y);
}

__global__ __launch_bounds__(TPB, 8) void fused_iou(
        const float* __restrict__ bboxes,
        const float* __restrict__ angles,
        float* __restrict__ out) {
    const int tid = threadIdx.x;
    const int b   = blockIdx.z;
    const int i0  = blockIdx.y * ITILE;
    const int j0  = blockIdx.x * JSPAN + tid * JQ;

    const float4* bb4 = reinterpret_cast<const float4*>(bboxes);

    // i-params: 16 lanes of wave 0 -> LDS (other waves proceed to j-params)
    __shared__ float sp[6][ITILE];
    if (tid < ITILE) {
        float cx, cy, A, B, D, R;
        box_params(bb4, angles, b * NBOX + i0 + tid, cx, cy, A, B, D, R);
        sp[0][tid] = cx; sp[1][tid] = cy; sp[2][tid] = A;
        sp[3][tid] = B;  sp[4][tid] = D;  sp[5][tid] = R;
    }

    // j-params: each thread computes its own 2 boxes into registers
    float c0, c1, y0v, y1v, A0, A1, B0, B1, D0, D1, R0, R1;
    box_params(bb4, angles, b * NBOX + j0 + 0, c0, y0v, A0, B0, D0, R0);
    box_params(bb4, angles, b * NBOX + j0 + 1, c1, y1v, A1, B1, D1, R1);
    float2 jux = f2(c0, c1);
    float2 juy = f2(y0v, y1v);
    float2 jA  = f2(A0, A1);
    float2 jB  = f2(B0, B1);
    float2 jD  = f2(D0, D1);
    float2 jR  = f2(R0, R1);

    __syncthreads();

    float* orow = out + ((size_t)(b * NBOX + i0)) * NBOX + j0;

    #pragma unroll 4
    for (int it = 0; it < ITILE; ++it) {
        float iux = sp[0][it];   // all-lane broadcast, conflict-free
        float iuy = sp[1][it];
        float ia  = sp[2][it];
        float ibv = sp[3][it];
        float id  = sp[4][it];
        float ir  = sp[5][it];

        float2 r = pair_duo(iux, iuy, ia, ibv, id, ir, jux, juy, jA, jB, jD, jR);

        // streaming output, never re-read: bypass L2/L3 allocation
        f32x2 rv;
        rv.x = r.x; rv.y = r.y;
        __builtin_nontemporal_store(rv, reinterpret_cast<f32x2*>(orow));
        orow += NBOX;
    }
}

extern "C" void kernel_launch(void* const* d_in, const int* in_sizes, int n_in,
                              void* d_out, int out_size, void* d_ws, size_t ws_size,
                              hipStream_t stream) {
    const float* bboxes = (const float*)d_in[0];
    const float* angles = (const float*)d_in[1];
    float* out = (float*)d_out;

    dim3 g(NBOX / JSPAN, NBOX / ITILE, BATCH);
    fused_iou<<<g, TPB, 0, stream>>>(bboxes, angles, out);
}